// Round 7
// baseline (41.898 us; speedup 1.0000x reference)
//
#include <hip/hip_runtime.h>
#include <hip/hip_bf16.h>
#include <math.h>

typedef float  f32x4  __attribute__((ext_vector_type(4)));
typedef short  bf16x8 __attribute__((ext_vector_type(8)));

#define NG  512
#define EPG 2048

// ---- LDS regions (80KB -> 2 blocks/CU) ----
#define B1_OFF 0        // phi buffer (layer input/output, rewritten in place)
#define B2_OFF 16384    // V1 = T0+T1 node-major (phase0: sAT f32 64x65, spills 256B into B3)
#define B3_OFF 32768    // V2 = T2 node-major (readout: sme/smx)
#define B4_OFF 49152    // V3 = T1 node-major (phase0: sdeg)
#define B5_OFF 65536    // Ln (8K) + L2n (8K); pS/pM reuse L2n space in last layer
#define LDS_SZ 81920
#define SASTR  65

static __device__ __forceinline__ unsigned short f2bf(float f) {
    union { __hip_bfloat16 b; unsigned short u; } c;
    c.b = __float2bfloat16(f);
    return c.u;
}
static __device__ __forceinline__ float bf2f(unsigned short h) {
    union { unsigned u; float f; } v; v.u = ((unsigned)h) << 16;
    return v.f;
}
static __device__ __forceinline__ unsigned pk2(float lo, float hi) {
    return (unsigned)f2bf(lo) | ((unsigned)f2bf(hi) << 16);
}
static __device__ __forceinline__ bf16x8 ubf(uint4 u) {
    union { uint4 a; bf16x8 b; } c; c.a = u; return c.b;
}
// phi layout: addr(n,f;F) = (n>>4)*(F/16)*512 + fpart(f) + (n&15)*2
static __device__ __forceinline__ int fpart(int f) {
    return ((((f >> 5) << 1) + ((f >> 2) & 1)) << 9) + (((f >> 3) & 3) << 7) + ((f & 3) << 5);
}

// ---------------------------------------------------------------------------
// wpack: pack per-layer weight B-fragments for the {V1,V2,V3} basis:
//   slot0 <- W[0]   (pairs V1 = T0+T1)
//   slot1 <- W[2]   (pairs V2 = T2)
//   slot2 <- W[1]-W[0] (pairs V3 = T1)
// frag(slot,kt,nt), slot(lane,j) = val[kt*32+lg*8+j][nt*16+li]
// ---------------------------------------------------------------------------
__global__ __launch_bounds__(64) void wpack(
    const float* __restrict__ W1, const float* __restrict__ W2,
    const float* __restrict__ W3, uint4* __restrict__ Wp)
{
    int b = blockIdx.x, lane = threadIdx.x;
    const float* W; int FIN, FOUT, rel, off;
    if (b < 48)       { W = W1; FIN = 64;  FOUT = 128; rel = b;       off = 0;   }
    else if (b < 144) { W = W2; FIN = 128; FOUT = 128; rel = b - 48;  off = 48;  }
    else              { W = W3; FIN = 128; FOUT = 64;  rel = b - 144; off = 144; }
    int NKT = FIN / 32, NNT = FOUT / 16;
    int sl = rel / (NKT * NNT), r2 = rel % (NKT * NNT);
    int kt = r2 / NNT, nt = r2 % NNT;
    int lg = lane >> 4, li = lane & 15;
    int fin0 = kt*32 + lg*8, fout = nt*16 + li;
    unsigned v[4];
#pragma unroll
    for (int jp = 0; jp < 4; ++jp) {
        float a0, a1;
#pragma unroll
        for (int h = 0; h < 2; ++h) {
            const size_t base = (size_t)(fin0 + 2*jp + h) * FOUT + fout;
            const float w0 = W[base];
            const float w1v = W[(size_t)FIN*FOUT + base];
            const float w2v = W[(size_t)2*FIN*FOUT + base];
            const float val = (sl == 0) ? w0 : (sl == 1) ? w2v : (w1v - w0);
            if (h == 0) a0 = val; else a1 = val;
        }
        v[jp] = pk2(a0, a1);
    }
    Wp[(size_t)(off + rel)*64 + lane] = make_uint4(v[0],v[1],v[2],v[3]);
}

// ---------------------------------------------------------------------------
// One ChebConv layer: prop (V3=L@T0, V2=L2@T0, V1=V3+T0) | bar |
// weight (out = V1 Wp0 + V2 Wp1 + V3 Wp2) + epilogue | bar.
// Layer input/output in phi layout at B1 (in-place); V's node-major swizzled.
// ---------------------------------------------------------------------------
template <int FIN, int FOUT, bool RELU, bool LAST>
static __device__ __forceinline__ void layer(
    char* smem, const uint4* __restrict__ Wp, const float* __restrict__ bias,
    int w, int lg, int li, int lane)
{
    constexpr int NKT = FIN / 32;
    constexpr int NNT = FOUT / 16;
    constexpr int NFO = FOUT / 32;
    constexpr int TST = FIN * 2;                 // V row stride (bytes)
    constexpr int TSM = (FIN == 128) ? 15 : 7;
    constexpr int NGS = (FIN >> 4) * 512;        // phi node-group stride

    char* Hio = smem + B1_OFF;
    char* V1  = smem + B2_OFF;
    char* V2  = smem + B3_OFF;
    char* V3  = smem + B4_OFF;
    const char* Ln  = smem + B5_OFF;
    const char* L2n = smem + B5_OFF + 8192;

    // ---------------- prop
    {
        const int mt  = (FIN == 128) ? w : (w & 3);
        const int nt0 = (FIN == 128) ? 0 : ((w >> 2) * 2);
        constexpr int NTN = (FIN == 128) ? 4 : 2;
        const int f  = mt * 16 + li;
        const int fp = fpart(f) + ((lg & 1) << 4);
        bf16x8 a[2];
#pragma unroll
        for (int kt = 0; kt < 2; ++kt)   // A[f][node kt*32+lg*8+j]
            a[kt] = *(const bf16x8*)(Hio + (kt * 2 + (lg >> 1)) * NGS + fp);
        const int fb    = mt * 16 + lg * 4;
        const int fpb   = fpart(fb);
        const int fcol2 = fb * 2;
#pragma unroll
        for (int j = 0; j < NTN; ++j) {
            const int nrow = (nt0 + j) * 16 + li;
            const int lsw  = (nrow & 7) << 4;
            f32x4 p2 = {0.f,0.f,0.f,0.f}, p3 = {0.f,0.f,0.f,0.f};
#pragma unroll
            for (int kt = 0; kt < 2; ++kt) {
                uint4 bL  = *(const uint4*)(Ln  + nrow*128 + ((kt*64 + lg*16) ^ lsw));
                uint4 bL2 = *(const uint4*)(L2n + nrow*128 + ((kt*64 + lg*16) ^ lsw));
                p3 = __builtin_amdgcn_mfma_f32_16x16x32_bf16(a[kt], ubf(bL),  p3, 0,0,0);
                p2 = __builtin_amdgcn_mfma_f32_16x16x32_bf16(a[kt], ubf(bL2), p2, 0,0,0);
            }
            // T0[nrow][fb+r] from phi (verified address path)
            const char* t0p = Hio + (nt0 + j) * NGS + fpb + li * 2;
            float t0v[4];
#pragma unroll
            for (int r = 0; r < 4; ++r)
                t0v[r] = bf2f(*(const unsigned short*)(t0p + r * 32));
            const int cb = fcol2 ^ ((nrow & TSM) << 4);
            *(uint2*)(V1 + nrow*TST + cb) =
                make_uint2(pk2(p3[0]+t0v[0], p3[1]+t0v[1]), pk2(p3[2]+t0v[2], p3[3]+t0v[3]));
            *(uint2*)(V2 + nrow*TST + cb) = make_uint2(pk2(p2[0],p2[1]), pk2(p2[2],p2[3]));
            *(uint2*)(V3 + nrow*TST + cb) = make_uint2(pk2(p3[0],p3[1]), pk2(p3[2],p3[3]));
        }
    }
    __syncthreads();

    // ---------------- weight + epilogue
    const int mw = w & 3, foh = w >> 2;
    f32x4 acc[NFO];
#pragma unroll
    for (int i = 0; i < NFO; ++i) acc[i] = (f32x4){0.f,0.f,0.f,0.f};
    {
        const int arow = mw * 16 + li;
        const int asw  = (arow & TSM) << 4;
#pragma unroll
        for (int sl = 0; sl < 3; ++sl) {
            const char* src = (sl == 0) ? V1 : (sl == 1) ? V2 : V3;
#pragma unroll
            for (int k = 0; k < NKT; ++k) {
                bf16x8 ta = *(const bf16x8*)(src + arow*TST + ((k*64 + lg*16) ^ asw));
#pragma unroll
                for (int fi = 0; fi < NFO; ++fi) {
                    uint4 wf = Wp[((size_t)(sl*NKT + k)*NNT + foh*NFO + fi)*64 + lane];
                    acc[fi] = __builtin_amdgcn_mfma_f32_16x16x32_bf16(ta, ubf(wf), acc[fi], 0,0,0);
                }
            }
        }
    }
    if (!LAST) {
        constexpr int OGS = (FOUT >> 4) * 512;
#pragma unroll
        for (int fi = 0; fi < NFO; ++fi) {
            const int fo = (foh*NFO + fi)*16 + li;
            const float bv = bias[fo];
            f32x4 v = acc[fi];
            float o0 = v[0]+bv, o1 = v[1]+bv, o2 = v[2]+bv, o3 = v[3]+bv;
            if (RELU) { o0=fmaxf(o0,0.f); o1=fmaxf(o1,0.f); o2=fmaxf(o2,0.f); o3=fmaxf(o3,0.f); }
            // nodes mw*16+lg*4..+3 contiguous in phi -> uint2
            *(uint2*)(Hio + mw*OGS + fpart(fo) + lg*8) =
                make_uint2(pk2(o0,o1), pk2(o2,o3));
        }
    } else {
        float* pS = (float*)(smem + B5_OFF + 8192);   // L2n dead after last prop
        float* pM = pS + 256;
#pragma unroll
        for (int fi = 0; fi < NFO; ++fi) {
            const int fo = (foh*NFO + fi)*16 + li;
            f32x4 v = acc[fi];
            float s = v[0]+v[1]+v[2]+v[3];
            float m = fmaxf(fmaxf(v[0],v[1]), fmaxf(v[2],v[3]));
            s += __shfl_xor(s, 16); s += __shfl_xor(s, 32);
            m = fmaxf(m, __shfl_xor(m, 16)); m = fmaxf(m, __shfl_xor(m, 32));
            if (lg == 0) { pS[mw*64 + fo] = s; pM[mw*64 + fo] = m; }
        }
    }
    __syncthreads();
}

// ---------------------------------------------------------------------------
// fused: L_hat + (2L^2-I) operators -> 3 ChebConv layers -> meanmax + FC.
// One block (512 threads, 8 waves) per graph; 80KB LDS -> 2 blocks/CU.
// ---------------------------------------------------------------------------
__global__ __launch_bounds__(512, 4) void fused(
    const float* __restrict__ X,  const float* __restrict__ ew,
    const int* __restrict__ row,  const int* __restrict__ col,
    const uint4* __restrict__ Wp,
    const float* __restrict__ b1, const float* __restrict__ b2,
    const float* __restrict__ b3,
    const float* __restrict__ fcw, const float* __restrict__ fcb,
    float* __restrict__ outp)
{
    __shared__ __align__(16) char smem[LDS_SZ];
    const int g = blockIdx.x, t = threadIdx.x;
    const int w = t >> 6, lane = t & 63, lg = lane >> 4, li = lane & 15;

    // ---- early global loads (hide HBM latency under phase 0)
    const float4* xg = (const float4*)(X + (size_t)g * 4096);
    float4 xv0 = xg[t], xv1 = xg[t + 512];
    const int e0 = g * EPG;
    int er[4], ec[4]; float ev[4];
#pragma unroll
    for (int j = 0; j < 4; ++j) {
        er[j] = row[e0 + t + 512*j] & 63;
        ec[j] = col[e0 + t + 512*j] & 63;
        ev[j] = ew[e0 + t + 512*j];
    }

    float* sAT  = (float*)(smem + B2_OFF);   // sAT[c][r] (stride 65): raw ew sums
    float* sdeg = (float*)(smem + B4_OFF);

    // ---- 0a: zero
    for (int i = t; i < 64 * SASTR; i += 512) sAT[i] = 0.f;
    if (t < 64) sdeg[t] = 0.f;
    __syncthreads();
    // ---- 0b: scatter (adjacency + degree in one pass)
#pragma unroll
    for (int j = 0; j < 4; ++j) {
        atomicAdd(&sAT[ec[j]*SASTR + er[j]], ev[j]);
        atomicAdd(&sdeg[er[j]], ev[j]);
    }
    __syncthreads();
    // ---- 0c: normalize in place (sAT[n][k] -> L[n][k]) + pack Ln + stage x->phi
    {
        const int n = t >> 3, k0 = (t & 7) * 8;
        const float dsn = sdeg[n];
        const float dn = dsn > 0.f ? rsqrtf(dsn) : 0.f;
        float vv[8];
#pragma unroll
        for (int j = 0; j < 8; ++j) {
            const float dk0 = sdeg[k0 + j];
            const float dk = dk0 > 0.f ? rsqrtf(dk0) : 0.f;
            const float v = -sAT[n*SASTR + k0 + j] * dk * dn;
            sAT[n*SASTR + k0 + j] = v;
            vv[j] = v;
        }
        *(uint4*)(smem + B5_OFF + n*128 + ((k0*2) ^ ((n & 7) << 4))) =
            make_uint4(pk2(vv[0],vv[1]), pk2(vv[2],vv[3]), pk2(vv[4],vv[5]), pk2(vv[6],vv[7]));
#pragma unroll
        for (int half = 0; half < 2; ++half) {
            const int i = t + half * 512;
            const float4 v = half ? xv1 : xv0;
            const int node = i >> 4, f0 = (i & 15) * 4;
            char* base = smem + B1_OFF + ((node >> 4) * 2048) + ((node & 15) << 1);
            *(unsigned short*)(base + fpart(f0 + 0)) = f2bf(v.x);
            *(unsigned short*)(base + fpart(f0 + 1)) = f2bf(v.y);
            *(unsigned short*)(base + fpart(f0 + 2)) = f2bf(v.z);
            *(unsigned short*)(base + fpart(f0 + 3)) = f2bf(v.w);
        }
    }
    __syncthreads();
    // ---- 0d: L2n[n][k] = (2L^2 - I)[n][k] via MFMA
    {
        const int mt2 = w & 3, nth = w >> 2;
        const int k1 = mt2*16 + li;
        bf16x8 a2[2];   // A[k1][m] = L[m][k1] = sAT[m][k1] (column read)
#pragma unroll
        for (int kt = 0; kt < 2; ++kt) {
            float av[8];
#pragma unroll
            for (int j = 0; j < 8; ++j)
                av[j] = sAT[(kt*32 + lg*8 + j)*SASTR + k1];
            union { uint4 u; bf16x8 b; } c;
            c.u = make_uint4(pk2(av[0],av[1]), pk2(av[2],av[3]),
                             pk2(av[4],av[5]), pk2(av[6],av[7]));
            a2[kt] = c.b;
        }
#pragma unroll
        for (int j = 0; j < 2; ++j) {
            const int nrow = (nth*2 + j)*16 + li;
            const int lsw  = (nrow & 7) << 4;
            f32x4 p = {0.f,0.f,0.f,0.f};
#pragma unroll
            for (int kt = 0; kt < 2; ++kt) {
                uint4 bf = *(const uint4*)(smem + B5_OFF + nrow*128 + ((kt*64 + lg*16) ^ lsw));
                p = __builtin_amdgcn_mfma_f32_16x16x32_bf16(a2[kt], ubf(bf), p, 0,0,0);
            }
            unsigned short q[4];
#pragma unroll
            for (int r = 0; r < 4; ++r) {
                const int kk = mt2*16 + lg*4 + r;
                q[r] = f2bf(2.f*p[r] - ((kk == nrow) ? 1.f : 0.f));
            }
            *(uint2*)(smem + B5_OFF + 8192 + nrow*128 + (((mt2*16 + lg*4)*2) ^ lsw)) =
                make_uint2(q[0] | ((unsigned)q[1] << 16), q[2] | ((unsigned)q[3] << 16));
        }
    }
    __syncthreads();

    // ---- 3 layers (phi in place at B1)
    layer<64, 128, true,  false>(smem, Wp,                  b1, w, lg, li, lane);
    layer<128, 128, true, false>(smem, Wp + (size_t)48*64,  b2, w, lg, li, lane);
    layer<128, 64, false, true >(smem, Wp + (size_t)144*64, b3, w, lg, li, lane);

    // ---- readout: combine node-tile partials, then FC
    float* pS  = (float*)(smem + B5_OFF + 8192);
    float* pM  = pS + 256;
    float* sme = (float*)(smem + B3_OFF);
    float* smx = sme + 64;
    if (t < 64) {
        float s = pS[t] + pS[64+t] + pS[128+t] + pS[192+t];
        float m = fmaxf(fmaxf(pM[t], pM[64+t]), fmaxf(pM[128+t], pM[192+t]));
        sme[t] = s * (1.f/64.f) + b3[t];
        smx[t] = m + b3[t];
    }
    __syncthreads();
    if (t < 64) {
        float a = fcb[t];
        for (int f2 = 0; f2 < 64; ++f2)
            a += sme[f2]*fcw[f2*64 + t] + smx[f2]*fcw[(64 + f2)*64 + t];
        outp[(size_t)g*64 + t] = a;
    }
}

// ---------------------------------------------------------------------------
extern "C" void kernel_launch(void* const* d_in, const int* in_sizes, int n_in,
                              void* d_out, int out_size, void* d_ws, size_t ws_size,
                              hipStream_t stream)
{
    const float* x   = (const float*)d_in[0];
    const float* ew  = (const float*)d_in[1];
    const float* W1  = (const float*)d_in[2];
    const float* b1  = (const float*)d_in[3];
    const float* W2  = (const float*)d_in[4];
    const float* b2  = (const float*)d_in[5];
    const float* W3  = (const float*)d_in[6];
    const float* b3  = (const float*)d_in[7];
    const float* fcw = (const float*)d_in[8];
    const float* fcb = (const float*)d_in[9];
    const int*   row = (const int*)d_in[10];
    const int*   col = (const int*)d_in[11];

    uint4* Wp = (uint4*)d_ws;   // 192 frags * 64 lanes * 16B = 192KB

    wpack<<<192, 64, 0, stream>>>(W1, W2, W3, Wp);
    fused<<<NG, 512, 0, stream>>>(x, ew, row, col, Wp,
                                  b1, b2, b3, fcw, fcb, (float*)d_out);
}

// Round 8
// 40.874 us; speedup vs baseline: 1.0250x; 1.0250x over previous
//
#include <hip/hip_runtime.h>
#include <hip/hip_bf16.h>
#include <math.h>

typedef float  f32x4  __attribute__((ext_vector_type(4)));
typedef short  bf16x8 __attribute__((ext_vector_type(8)));

#define NG  512
#define EPG 2048

// ---- LDS regions (80KB -> 2 blocks/CU) ----
#define B1_OFF 0        // Ht feat-major [F][64] bf16, 128B rows, swz (row&7)<<4 (layer io, in place)
#define B2_OFF 16384    // V1 = T0+T1 node-major (phase0: sAT f32 64x65, spills 256B into B3)
#define B3_OFF 32768    // V2 = T2 node-major (readout: sme/smx/part)
#define B4_OFF 49152    // V3 = T1 node-major (phase0: sdeg)
#define B5_OFF 65536    // Ln (8K) + L2n (8K); pS/pM reuse L2n space in last layer
#define LDS_SZ 81920
#define SASTR  65

static __device__ __forceinline__ unsigned short f2bf(float f) {
    union { __hip_bfloat16 b; unsigned short u; } c;
    c.b = __float2bfloat16(f);
    return c.u;
}
static __device__ __forceinline__ float bf2f(unsigned short h) {
    union { unsigned u; float f; } v; v.u = ((unsigned)h) << 16;
    return v.f;
}
static __device__ __forceinline__ unsigned pk2(float lo, float hi) {
    return (unsigned)f2bf(lo) | ((unsigned)f2bf(hi) << 16);
}
static __device__ __forceinline__ bf16x8 ubf(uint4 u) {
    union { uint4 a; bf16x8 b; } c; c.a = u; return c.b;
}

// ---------------------------------------------------------------------------
// wpack: pack per-layer weight B-fragments for the {V1,V2,V3} basis (r7-verified):
//   slot0 <- W[0] (pairs V1=T0+T1), slot1 <- W[2] (pairs V2=T2), slot2 <- W[1]-W[0] (pairs V3=T1)
// frag(slot,kt,nt), slot(lane,j) = val[kt*32+lg*8+j][nt*16+li]
// ---------------------------------------------------------------------------
__global__ __launch_bounds__(64) void wpack(
    const float* __restrict__ W1, const float* __restrict__ W2,
    const float* __restrict__ W3, uint4* __restrict__ Wp)
{
    int b = blockIdx.x, lane = threadIdx.x;
    const float* W; int FIN, FOUT, rel, off;
    if (b < 48)       { W = W1; FIN = 64;  FOUT = 128; rel = b;       off = 0;   }
    else if (b < 144) { W = W2; FIN = 128; FOUT = 128; rel = b - 48;  off = 48;  }
    else              { W = W3; FIN = 128; FOUT = 64;  rel = b - 144; off = 144; }
    int NKT = FIN / 32, NNT = FOUT / 16;
    int sl = rel / (NKT * NNT), r2 = rel % (NKT * NNT);
    int kt = r2 / NNT, nt = r2 % NNT;
    int lg = lane >> 4, li = lane & 15;
    int fin0 = kt*32 + lg*8, fout = nt*16 + li;
    unsigned v[4];
#pragma unroll
    for (int jp = 0; jp < 4; ++jp) {
        float a0, a1;
#pragma unroll
        for (int h = 0; h < 2; ++h) {
            const size_t base = (size_t)(fin0 + 2*jp + h) * FOUT + fout;
            const float w0  = W[base];
            const float w1v = W[(size_t)FIN*FOUT + base];
            const float w2v = W[(size_t)2*FIN*FOUT + base];
            const float val = (sl == 0) ? w0 : (sl == 1) ? w2v : (w1v - w0);
            if (h == 0) a0 = val; else a1 = val;
        }
        v[jp] = pk2(a0, a1);
    }
    Wp[(size_t)(off + rel)*64 + lane] = make_uint4(v[0],v[1],v[2],v[3]);
}

// ---------------------------------------------------------------------------
// One ChebConv layer: prop (V3=T~0@L^T, V2=T~0@L2^T, V1=V3+T0) | bar |
// weight (out = V1 Wp0 + V2 Wp1 + V3 Wp2) + epilogue -> Ht in place | bar.
// Ht feat-major (r5-verified access patterns); V's node-major swizzled.
// ---------------------------------------------------------------------------
template <int FIN, int FOUT, bool RELU, bool LAST>
static __device__ __forceinline__ void layer(
    char* smem, const uint4* __restrict__ Wp, const float* __restrict__ bias,
    int w, int lg, int li, int lane)
{
    constexpr int NKT = FIN / 32;
    constexpr int NNT = FOUT / 16;
    constexpr int NFO = FOUT / 32;
    constexpr int TST = FIN * 2;                 // V row stride (bytes)
    constexpr int TSM = (FIN == 128) ? 15 : 7;

    char* Ht = smem + B1_OFF;
    char* V1 = smem + B2_OFF;
    char* V2 = smem + B3_OFF;
    char* V3 = smem + B4_OFF;
    const char* Ln  = smem + B5_OFF;
    const char* L2n = smem + B5_OFF + 8192;

    // ---------------- prop
    {
        const int mt  = (FIN == 128) ? w : (w & 3);
        const int nt0 = (FIN == 128) ? 0 : ((w >> 2) * 2);
        constexpr int NTN = (FIN == 128) ? 4 : 2;
        const int frow = mt * 16 + li;
        const int fsw  = (frow & 7) << 4;
        bf16x8 a[2];
#pragma unroll
        for (int kt = 0; kt < 2; ++kt)   // T~0[frow][nodes kt*32+lg*8+..]
            a[kt] = *(const bf16x8*)(Ht + frow*128 + ((kt*64 + lg*16) ^ fsw));
        const int fb = mt * 16 + lg * 4;
#pragma unroll
        for (int j = 0; j < NTN; ++j) {
            const int nrow = (nt0 + j) * 16 + li;
            const int lsw  = (nrow & 7) << 4;
            f32x4 p2 = {0.f,0.f,0.f,0.f}, p3 = {0.f,0.f,0.f,0.f};
#pragma unroll
            for (int kt = 0; kt < 2; ++kt) {
                uint4 bL  = *(const uint4*)(Ln  + nrow*128 + ((kt*64 + lg*16) ^ lsw));
                uint4 bL2 = *(const uint4*)(L2n + nrow*128 + ((kt*64 + lg*16) ^ lsw));
                p3 = __builtin_amdgcn_mfma_f32_16x16x32_bf16(a[kt], ubf(bL),  p3, 0,0,0);
                p2 = __builtin_amdgcn_mfma_f32_16x16x32_bf16(a[kt], ubf(bL2), p2, 0,0,0);
            }
            // T0[nrow][fb+r] = Ht[fb+r][nrow] (column read, ~2-way)
            float t0v[4];
#pragma unroll
            for (int r = 0; r < 4; ++r)
                t0v[r] = bf2f(*(const unsigned short*)(
                    Ht + (fb + r)*128 + ((nrow*2) ^ (((fb + r) & 7) << 4))));
            const int cb = (fb * 2) ^ ((nrow & TSM) << 4);
            *(uint2*)(V1 + nrow*TST + cb) =
                make_uint2(pk2(p3[0]+t0v[0], p3[1]+t0v[1]), pk2(p3[2]+t0v[2], p3[3]+t0v[3]));
            *(uint2*)(V2 + nrow*TST + cb) = make_uint2(pk2(p2[0],p2[1]), pk2(p2[2],p2[3]));
            *(uint2*)(V3 + nrow*TST + cb) = make_uint2(pk2(p3[0],p3[1]), pk2(p3[2],p3[3]));
        }
    }
    __syncthreads();

    // ---------------- weight + epilogue
    const int mw = w & 3, foh = w >> 2;
    f32x4 acc[NFO];
#pragma unroll
    for (int i = 0; i < NFO; ++i) acc[i] = (f32x4){0.f,0.f,0.f,0.f};
    {
        const int arow = mw * 16 + li;
        const int asw  = (arow & TSM) << 4;
#pragma unroll
        for (int sl = 0; sl < 3; ++sl) {
            const char* src = (sl == 0) ? V1 : (sl == 1) ? V2 : V3;
#pragma unroll
            for (int k = 0; k < NKT; ++k) {
                bf16x8 ta = *(const bf16x8*)(src + arow*TST + ((k*64 + lg*16) ^ asw));
#pragma unroll
                for (int fi = 0; fi < NFO; ++fi) {
                    uint4 wf = Wp[((size_t)(sl*NKT + k)*NNT + foh*NFO + fi)*64 + lane];
                    acc[fi] = __builtin_amdgcn_mfma_f32_16x16x32_bf16(ta, ubf(wf), acc[fi], 0,0,0);
                }
            }
        }
    }
    if (!LAST) {
#pragma unroll
        for (int fi = 0; fi < NFO; ++fi) {
            const int fo = (foh*NFO + fi)*16 + li;
            const float bv = bias[fo];
            f32x4 v = acc[fi];
            float o0 = v[0]+bv, o1 = v[1]+bv, o2 = v[2]+bv, o3 = v[3]+bv;
            if (RELU) { o0=fmaxf(o0,0.f); o1=fmaxf(o1,0.f); o2=fmaxf(o2,0.f); o3=fmaxf(o3,0.f); }
            const int node0 = mw*16 + lg*4;
            // Ht[fo][node0..node0+3] (r5-verified write pattern)
            *(uint2*)(smem + B1_OFF + fo*128 + ((node0*2) ^ ((fo & 7) << 4))) =
                make_uint2(pk2(o0,o1), pk2(o2,o3));
        }
    } else {
        float* pS = (float*)(smem + B5_OFF + 8192);   // L2n dead after last prop
        float* pM = pS + 256;
#pragma unroll
        for (int fi = 0; fi < NFO; ++fi) {
            const int fo = (foh*NFO + fi)*16 + li;
            f32x4 v = acc[fi];
            float s = v[0]+v[1]+v[2]+v[3];
            float m = fmaxf(fmaxf(v[0],v[1]), fmaxf(v[2],v[3]));
            s += __shfl_xor(s, 16); s += __shfl_xor(s, 32);
            m = fmaxf(m, __shfl_xor(m, 16)); m = fmaxf(m, __shfl_xor(m, 32));
            if (lg == 0) { pS[mw*64 + fo] = s; pM[mw*64 + fo] = m; }
        }
    }
    __syncthreads();
}

// ---------------------------------------------------------------------------
// fused: L_hat + (2L^2-I) operators -> 3 ChebConv layers -> meanmax + FC.
// One block (512 threads, 8 waves) per graph; 80KB LDS -> 2 blocks/CU.
// ---------------------------------------------------------------------------
__global__ __launch_bounds__(512, 4) void fused(
    const float* __restrict__ X,  const float* __restrict__ ew,
    const int* __restrict__ row,  const int* __restrict__ col,
    const uint4* __restrict__ Wp,
    const float* __restrict__ b1, const float* __restrict__ b2,
    const float* __restrict__ b3,
    const float* __restrict__ fcw, const float* __restrict__ fcb,
    float* __restrict__ outp)
{
    __shared__ __align__(16) char smem[LDS_SZ];
    const int g = blockIdx.x, t = threadIdx.x;
    const int w = t >> 6, lane = t & 63, lg = lane >> 4, li = lane & 15;

    // ---- early global loads (hide HBM latency under phase 0)
    const float4* xg = (const float4*)(X + (size_t)g * 4096);
    float4 xv0 = xg[t], xv1 = xg[t + 512];
    const int e0 = g * EPG;
    int er[4], ec[4]; float ev[4];
#pragma unroll
    for (int j = 0; j < 4; ++j) {
        er[j] = row[e0 + t + 512*j] & 63;
        ec[j] = col[e0 + t + 512*j] & 63;
        ev[j] = ew[e0 + t + 512*j];
    }

    float* sAT  = (float*)(smem + B2_OFF);   // sAT[c][r] (stride 65): raw ew sums
    float* sdeg = (float*)(smem + B4_OFF);

    // ---- 0a: zero
    for (int i = t; i < 64 * SASTR; i += 512) sAT[i] = 0.f;
    if (t < 64) sdeg[t] = 0.f;
    __syncthreads();
    // ---- 0b: scatter (adjacency + degree in one pass)
#pragma unroll
    for (int j = 0; j < 4; ++j) {
        atomicAdd(&sAT[ec[j]*SASTR + er[j]], ev[j]);
        atomicAdd(&sdeg[er[j]], ev[j]);
    }
    __syncthreads();
    // ---- 0c: normalize in place (sAT[n][k] -> L[n][k]) + pack Ln + stage x->Ht
    {
        const int n = t >> 3, k0 = (t & 7) * 8;
        const float dsn = sdeg[n];
        const float dn = dsn > 0.f ? rsqrtf(dsn) : 0.f;
        float vv[8];
#pragma unroll
        for (int j = 0; j < 8; ++j) {
            const float dk0 = sdeg[k0 + j];
            const float dk = dk0 > 0.f ? rsqrtf(dk0) : 0.f;
            const float v = -sAT[n*SASTR + k0 + j] * dk * dn;
            sAT[n*SASTR + k0 + j] = v;
            vv[j] = v;
        }
        *(uint4*)(smem + B5_OFF + n*128 + ((k0*2) ^ ((n & 7) << 4))) =
            make_uint4(pk2(vv[0],vv[1]), pk2(vv[2],vv[3]), pk2(vv[4],vv[5]), pk2(vv[6],vv[7]));
#pragma unroll
        for (int half = 0; half < 2; ++half) {
            const int i = t + half * 512;
            const float4 v = half ? xv1 : xv0;
            const int node = i >> 4, f0 = (i & 15) * 4;
            unsigned short h[4] = { f2bf(v.x), f2bf(v.y), f2bf(v.z), f2bf(v.w) };
#pragma unroll
            for (int r = 0; r < 4; ++r)
                *(unsigned short*)(smem + B1_OFF + (f0+r)*128 +
                                   ((node*2) ^ (((f0+r) & 7) << 4))) = h[r];
        }
    }
    __syncthreads();
    // ---- 0d: L2n[n][k] = (2L^2 - I)[n][k] via MFMA (r7-verified)
    {
        const int mt2 = w & 3, nth = w >> 2;
        const int k1 = mt2*16 + li;
        bf16x8 a2[2];   // A[k1][m] = L[m][k1] = sAT[m][k1] (column read)
#pragma unroll
        for (int kt = 0; kt < 2; ++kt) {
            float av[8];
#pragma unroll
            for (int j = 0; j < 8; ++j)
                av[j] = sAT[(kt*32 + lg*8 + j)*SASTR + k1];
            union { uint4 u; bf16x8 b; } c;
            c.u = make_uint4(pk2(av[0],av[1]), pk2(av[2],av[3]),
                             pk2(av[4],av[5]), pk2(av[6],av[7]));
            a2[kt] = c.b;
        }
#pragma unroll
        for (int j = 0; j < 2; ++j) {
            const int nrow = (nth*2 + j)*16 + li;
            const int lsw  = (nrow & 7) << 4;
            f32x4 p = {0.f,0.f,0.f,0.f};
#pragma unroll
            for (int kt = 0; kt < 2; ++kt) {
                uint4 bf = *(const uint4*)(smem + B5_OFF + nrow*128 + ((kt*64 + lg*16) ^ lsw));
                p = __builtin_amdgcn_mfma_f32_16x16x32_bf16(a2[kt], ubf(bf), p, 0,0,0);
            }
            unsigned short q[4];
#pragma unroll
            for (int r = 0; r < 4; ++r) {
                const int kk = mt2*16 + lg*4 + r;
                q[r] = f2bf(2.f*p[r] - ((kk == nrow) ? 1.f : 0.f));
            }
            *(uint2*)(smem + B5_OFF + 8192 + nrow*128 + (((mt2*16 + lg*4)*2) ^ lsw)) =
                make_uint2(q[0] | ((unsigned)q[1] << 16), q[2] | ((unsigned)q[3] << 16));
        }
    }
    __syncthreads();

    // ---- 3 layers (Ht in place at B1)
    layer<64, 128, true,  false>(smem, Wp,                  b1, w, lg, li, lane);
    layer<128, 128, true, false>(smem, Wp + (size_t)48*64,  b2, w, lg, li, lane);
    layer<128, 64, false, true >(smem, Wp + (size_t)144*64, b3, w, lg, li, lane);

    // ---- readout: combine node-tile partials, then FC (2-wave split)
    float* pS   = (float*)(smem + B5_OFF + 8192);
    float* pM   = pS + 256;
    float* sme  = (float*)(smem + B3_OFF);
    float* smx  = sme + 64;
    float* part = smx + 64;
    if (t < 64) {
        float s = pS[t] + pS[64+t] + pS[128+t] + pS[192+t];
        float m = fmaxf(fmaxf(pM[t], pM[64+t]), fmaxf(pM[128+t], pM[192+t]));
        sme[t] = s * (1.f/64.f) + b3[t];
        smx[t] = m + b3[t];
    }
    __syncthreads();
    if (t < 128) {
        const int j = t & 63, h = t >> 6;
        const float* wv = fcw + (size_t)h*64*64;
        const float* sv = h ? smx : sme;
        float a = 0.f;
        for (int f2 = 0; f2 < 64; ++f2) a += sv[f2] * wv[f2*64 + j];
        part[t] = a;
    }
    __syncthreads();
    if (t < 64) outp[(size_t)g*64 + t] = part[t] + part[64 + t] + fcb[t];
}

// ---------------------------------------------------------------------------
extern "C" void kernel_launch(void* const* d_in, const int* in_sizes, int n_in,
                              void* d_out, int out_size, void* d_ws, size_t ws_size,
                              hipStream_t stream)
{
    const float* x   = (const float*)d_in[0];
    const float* ew  = (const float*)d_in[1];
    const float* W1  = (const float*)d_in[2];
    const float* b1  = (const float*)d_in[3];
    const float* W2  = (const float*)d_in[4];
    const float* b2  = (const float*)d_in[5];
    const float* W3  = (const float*)d_in[6];
    const float* b3  = (const float*)d_in[7];
    const float* fcw = (const float*)d_in[8];
    const float* fcb = (const float*)d_in[9];
    const int*   row = (const int*)d_in[10];
    const int*   col = (const int*)d_in[11];

    uint4* Wp = (uint4*)d_ws;   // 192 frags * 64 lanes * 16B = 192KB

    wpack<<<192, 64, 0, stream>>>(W1, W2, W3, Wp);
    fused<<<NG, 512, 0, stream>>>(x, ew, row, col, Wp,
                                  b1, b2, b3, fcw, fcb, (float*)d_out);
}